// Round 1
// baseline (864.465 us; speedup 1.0000x reference)
//
#include <hip/hip_runtime.h>
#include <hip/hip_bf16.h>

// SoftAttention fused pipeline for MI355X (gfx950).
// Shapes: feature (256,196,2048) f32, prev_h (256,512), W_enc (2048,512),
// W_dec (512,512), W_tot (512,1). Outputs: weighted_feature (256,2048),
// alpha (256,196), concatenated flat in d_out (fp32).
//
// Strategy:
//  K0: W_enc f32 -> bf16, transposed + k-step-tiled layout Bst[ks][kq][512][8]
//  K1: att2[n][a] = prev_h[n]@W_dec + b_dec + b_enc   (fp32, vector)
//  K2: scores GEMM: M=50176,N=512,K=2048 bf16 MFMA 16x16x32, 128x128 tiles,
//      epilogue: sum_a W_tot[a]*relu(acc + att2) -> atomicAdd(scores[row])
//      (b_tot dropped: softmax-invariant)
//  K3: softmax over L=196 per n -> alpha
//  K4: weighted_feature[n][d] = sum_l alpha[l]*feature[n][l][d] (float4)

typedef unsigned short u16;
typedef __attribute__((ext_vector_type(8))) short short8;  // 8 x bf16 (4 VGPR)
typedef __attribute__((ext_vector_type(4))) float f32x4;   // MFMA C/D frag

#define BATCH 256
#define LQ    196
#define DDIM  2048
#define ADIM  512
#define MTOT  (BATCH * LQ)   /* 50176 = 392 * 128 exactly */
#define WF_N  (BATCH * DDIM) /* 524288 */

__device__ __forceinline__ u16 f2bf(float f) {
  // round-to-nearest-even f32 -> bf16 (inputs are finite; no NaN handling)
  unsigned u = __builtin_bit_cast(unsigned, f);
  return (u16)((u + 0x7FFFu + ((u >> 16) & 1u)) >> 16);
}

__device__ __forceinline__ ushort4 cvt4(float4 f) {
  ushort4 r;
  r.x = f2bf(f.x); r.y = f2bf(f.y); r.z = f2bf(f.z); r.w = f2bf(f.w);
  return r;
}

// ---------------- K0: prep B = W_enc^T as bf16, layout [ks][kq][n=512][e=8]
// Bst element [ks][kq][n][e] = W_enc[ks*32 + kq*8 + e][n]
__global__ void prepB_k(const float* __restrict__ W_enc, u16* __restrict__ Bst) {
  const int ks = blockIdx.x;      // 0..63, k-step of 32
  const int tid = threadIdx.x;    // 256 threads
  __shared__ u16 ldsT[32 * 520];  // [d_local][n] stride 520 (pad vs bank conflicts)
  for (int i4 = tid; i4 < 4096; i4 += 256) {   // 32*512 floats / 4
    int dl = i4 >> 7;              // 0..31
    int nn = (i4 & 127) << 2;      // 0..508
    float4 f = *(const float4*)(W_enc + (size_t)(ks * 32 + dl) * 512 + nn);
    *(ushort4*)(&ldsT[dl * 520 + nn]) = cvt4(f);
  }
  __syncthreads();
  for (int idx = tid; idx < 16384; idx += 256) {
    int kq = idx >> 12;            // 0..3
    int n  = (idx >> 3) & 511;
    int e  = idx & 7;
    Bst[(size_t)ks * 16384 + idx] = ldsT[(kq * 8 + e) * 520 + n];
  }
}

// ---------------- K1: att2[n][a] = b_dec[a] + b_enc[a] + prev_h[n]@W_dec[:,a]
__global__ void att2_k(const float* __restrict__ prev_h,
                       const float* __restrict__ W_dec,
                       const float* __restrict__ b_dec,
                       const float* __restrict__ b_enc,
                       float* __restrict__ att2) {
  const int n = blockIdx.x, tid = threadIdx.x;
  __shared__ float ph[512];
  ph[tid]       = prev_h[n * 512 + tid];
  ph[tid + 256] = prev_h[n * 512 + tid + 256];
  __syncthreads();
  float a0 = b_dec[tid] + b_enc[tid];
  float a1 = b_dec[tid + 256] + b_enc[tid + 256];
  #pragma unroll 8
  for (int h = 0; h < 512; h++) {
    float p = ph[h];
    a0 = fmaf(p, W_dec[h * 512 + tid], a0);
    a1 = fmaf(p, W_dec[h * 512 + tid + 256], a1);
  }
  att2[n * 512 + tid] = a0;
  att2[n * 512 + tid + 256] = a1;
}

// ---------------- zero scores
__global__ void zero_scores_k(float* __restrict__ s) {
  s[blockIdx.x * 256 + threadIdx.x] = 0.f;   // grid 196*256 = 50176
}

// ---------------- K2: main GEMM + fused relu/W_tot reduce
// grid 1568 = 392 m-tiles * 4 n-tiles; block 256 thr = 4 waves (wave grid 2x2)
__global__ __launch_bounds__(256, 2) void score_gemm_k(
    const float* __restrict__ feature, const u16* __restrict__ Bst,
    const float* __restrict__ att2, const float* __restrict__ W_tot,
    float* __restrict__ scores) {
  __shared__ __align__(16) u16 sA[4096];   // [kq][row=128][8] bf16, 8 KB
  __shared__ __align__(16) u16 sB[4096];   // [kq][col=128][8] bf16, 8 KB
  __shared__ float sRed[2][128];

  const int tid = threadIdx.x;
  const int bx = blockIdx.x;
  const int mt = bx >> 2, nt = bx & 3;     // 4 n-siblings adjacent -> L3 A-share
  const int r0 = mt << 7, n0 = nt << 7;
  const int wid = tid >> 6, lane = tid & 63;
  const int wgm = wid >> 1, wgn = wid & 1;
  const int quad = lane >> 4, cid = lane & 15;

  // --- staging address setup
  const int arow = tid >> 3, akk4 = tid & 7;      // A slot: row, float4-within-row
  const float* gA = feature + (size_t)(r0 + arow) * 2048 + akk4 * 4;
  u16* wA = &sA[((akk4 >> 1) << 10) + (arow << 3) + ((akk4 & 1) << 2)];
  const int bkq = tid >> 7, bnl = tid & 127;      // B granule: kq, col
  const u16* gB = Bst + ((size_t)bkq << 12) + ((size_t)(n0 + bnl) << 3);
  u16* wB = &sB[tid << 3];

  // --- fragment read offsets (A: m=lane&15, k=quad*8+j ; B mirrored)
  const int abase = (quad << 10) + (((wgm << 6) + cid) << 3);
  const int bbase = (quad << 10) + (((wgn << 6) + cid) << 3);

  f32x4 zero = {0.f, 0.f, 0.f, 0.f};
  f32x4 acc[4][4];
  #pragma unroll
  for (int i = 0; i < 4; i++)
    #pragma unroll
    for (int j = 0; j < 4; j++) acc[i][j] = zero;

  for (int ks = 0; ks < 64; ks++) {
    __syncthreads();   // previous iter's ds_reads done before overwrite
    float4 a0 = *(const float4*)(gA + ks * 32);
    float4 a1 = *(const float4*)(gA + ks * 32 + 32 * 2048);
    float4 a2 = *(const float4*)(gA + ks * 32 + 64 * 2048);
    float4 a3 = *(const float4*)(gA + ks * 32 + 96 * 2048);
    uint4 b0 = *(const uint4*)(gB + (size_t)ks * 16384);
    uint4 b1 = *(const uint4*)(gB + (size_t)ks * 16384 + 8192);
    *(ushort4*)(wA)       = cvt4(a0);
    *(ushort4*)(wA + 256) = cvt4(a1);
    *(ushort4*)(wA + 512) = cvt4(a2);
    *(ushort4*)(wA + 768) = cvt4(a3);
    *(uint4*)(wB)        = b0;
    *(uint4*)(wB + 2048) = b1;
    __syncthreads();   // staging visible

    short8 af[4], bf[4];
    #pragma unroll
    for (int mi = 0; mi < 4; mi++)
      af[mi] = *(const short8*)(&sA[abase + (mi << 7)]);
    #pragma unroll
    for (int ni = 0; ni < 4; ni++)
      bf[ni] = *(const short8*)(&sB[bbase + (ni << 7)]);
    #pragma unroll
    for (int mi = 0; mi < 4; mi++)
      #pragma unroll
      for (int ni = 0; ni < 4; ni++)
        acc[mi][ni] = __builtin_amdgcn_mfma_f32_16x16x32_bf16(
            af[mi], bf[ni], acc[mi][ni], 0, 0, 0);
  }

  // --- epilogue: s[row] = sum_cols W_tot[col]*relu(acc + att2[n(row)][col])
  float wt[4];
  #pragma unroll
  for (int ni = 0; ni < 4; ni++)
    wt[ni] = W_tot[n0 + (wgn << 6) + ni * 16 + cid];

  #pragma unroll
  for (int mi = 0; mi < 4; mi++) {
    #pragma unroll
    for (int reg = 0; reg < 4; reg++) {
      int row_local = (wgm << 6) + mi * 16 + quad * 4 + reg;  // C/D: row=(lane>>4)*4+reg
      int row_flat = r0 + row_local;
      int nb = row_flat / 196;
      const float* a2r = att2 + nb * 512 + n0 + (wgn << 6);
      float s = 0.f;
      #pragma unroll
      for (int ni = 0; ni < 4; ni++) {
        float v = acc[mi][ni][reg] + a2r[ni * 16 + cid];      // C/D: col=lane&15
        s += fmaxf(v, 0.f) * wt[ni];
      }
      s += __shfl_xor(s, 1); s += __shfl_xor(s, 2);
      s += __shfl_xor(s, 4); s += __shfl_xor(s, 8);
      if (cid == 0) sRed[wgn][row_local] = s;
    }
  }
  __syncthreads();
  if (tid < 128) atomicAdd(&scores[r0 + tid], sRed[0][tid] + sRed[1][tid]);
}

// ---------------- K3: softmax over L per n (b_tot dropped: shift-invariant)
__global__ void softmax_k(const float* __restrict__ scores,
                          float* __restrict__ alpha) {
  const int n = blockIdx.x, tid = threadIdx.x;
  __shared__ float red[8];
  float s = (tid < LQ) ? scores[n * LQ + tid] : -1e30f;
  float m = s;
  for (int o = 32; o; o >>= 1) m = fmaxf(m, __shfl_xor(m, o));
  if ((tid & 63) == 0) red[tid >> 6] = m;
  __syncthreads();
  m = fmaxf(fmaxf(red[0], red[1]), fmaxf(red[2], red[3]));
  float e = (tid < LQ) ? __expf(s - m) : 0.f;
  float t = e;
  for (int o = 32; o; o >>= 1) t += __shfl_xor(t, o);
  if ((tid & 63) == 0) red[4 + (tid >> 6)] = t;
  __syncthreads();
  t = red[4] + red[5] + red[6] + red[7];
  if (tid < LQ) alpha[n * LQ + tid] = e / t;
}

// ---------------- K4: weighted_feature[n][d] = sum_l alpha[l]*feature[n][l][d]
__global__ void wsum_k(const float* __restrict__ feature,
                       const float* __restrict__ alpha,
                       float* __restrict__ out) {
  const int n = blockIdx.x >> 1, half = blockIdx.x & 1;
  const int tid = threadIdx.x;
  __shared__ float al[LQ];
  if (tid < LQ) al[tid] = alpha[n * LQ + tid];
  __syncthreads();
  const float* fp = feature + (size_t)n * LQ * DDIM + half * 1024 + tid * 4;
  float4 acc = {0.f, 0.f, 0.f, 0.f};
  #pragma unroll 4
  for (int l = 0; l < LQ; l++) {
    float a = al[l];
    float4 f = *(const float4*)(fp + (size_t)l * DDIM);
    acc.x = fmaf(a, f.x, acc.x); acc.y = fmaf(a, f.y, acc.y);
    acc.z = fmaf(a, f.z, acc.z); acc.w = fmaf(a, f.w, acc.w);
  }
  *(float4*)(out + n * DDIM + half * 1024 + tid * 4) = acc;
}

extern "C" void kernel_launch(void* const* d_in, const int* in_sizes, int n_in,
                              void* d_out, int out_size, void* d_ws, size_t ws_size,
                              hipStream_t stream) {
  const float* feature = (const float*)d_in[0];
  const float* prev_h  = (const float*)d_in[1];
  const float* W_enc   = (const float*)d_in[2];
  const float* b_enc   = (const float*)d_in[3];
  const float* W_dec   = (const float*)d_in[4];
  const float* b_dec   = (const float*)d_in[5];
  const float* W_tot   = (const float*)d_in[6];
  // d_in[7] = b_tot: softmax-invariant for alpha, unused

  float* out   = (float*)d_out;
  float* wf    = out;            // 524288 floats
  float* alpha = out + WF_N;     // 50176 floats

  char* ws = (char*)d_ws;
  u16*   Bst    = (u16*)ws;                              // 2 MB
  float* att2   = (float*)(ws + (2u << 20));             // 512 KB
  float* scores = (float*)(ws + (2u << 20) + (512u << 10)); // 200704 B

  prepB_k<<<64, 256, 0, stream>>>(W_enc, Bst);
  att2_k<<<256, 256, 0, stream>>>(prev_h, W_dec, b_dec, b_enc, att2);
  zero_scores_k<<<196, 256, 0, stream>>>(scores);
  score_gemm_k<<<1568, 256, 0, stream>>>(feature, Bst, att2, W_tot, scores);
  softmax_k<<<256, 256, 0, stream>>>(scores, alpha);
  wsum_k<<<512, 256, 0, stream>>>(feature, alpha, wf);
}

// Round 2
// 775.902 us; speedup vs baseline: 1.1141x; 1.1141x over previous
//
#include <hip/hip_runtime.h>
#include <hip/hip_bf16.h>

// SoftAttention fused pipeline for MI355X (gfx950).
// R2: score_gemm_k rewritten — software-pipelined double-buffered LDS,
// global_load_lds(16B) for B, XCD-grouped swizzle (4 n-siblings of an
// m-panel on one XCD, adjacent dispatch), padded LDS kq-plane stride
// (1032 elem = 516 dwords == 4 mod 32) to kill staging bank conflicts.

typedef unsigned short u16;
typedef __attribute__((ext_vector_type(8))) short short8;  // 8 x bf16 (4 VGPR)
typedef __attribute__((ext_vector_type(4))) float f32x4;   // MFMA C/D frag

#define BATCH 256
#define LQ    196
#define DDIM  2048
#define ADIM  512
#define MTOT  (BATCH * LQ)   /* 50176 = 392 * 128 exactly */
#define WF_N  (BATCH * DDIM) /* 524288 */
#define KQP   1032           /* padded kq-plane stride in u16 elements */

__device__ __forceinline__ u16 f2bf(float f) {
  unsigned u = __builtin_bit_cast(unsigned, f);
  return (u16)((u + 0x7FFFu + ((u >> 16) & 1u)) >> 16);
}

__device__ __forceinline__ ushort4 cvt4(float4 f) {
  ushort4 r;
  r.x = f2bf(f.x); r.y = f2bf(f.y); r.z = f2bf(f.z); r.w = f2bf(f.w);
  return r;
}

__device__ __forceinline__ void glds16(const u16* g, u16* l) {
  // global -> LDS direct copy, 16 B per lane; LDS dest = uniform base + lane*16
  __builtin_amdgcn_global_load_lds(
      (const __attribute__((address_space(1))) unsigned int*)g,
      (__attribute__((address_space(3))) unsigned int*)l, 16, 0, 0);
}

// ---------------- K0: prep B = W_enc^T as bf16, layout [ks][kq][n=512][e=8]
__global__ void prepB_k(const float* __restrict__ W_enc, u16* __restrict__ Bst) {
  const int ks = blockIdx.x;      // 0..63
  const int tid = threadIdx.x;    // 256
  __shared__ u16 ldsT[32 * 520];
  for (int i4 = tid; i4 < 4096; i4 += 256) {
    int dl = i4 >> 7;
    int nn = (i4 & 127) << 2;
    float4 f = *(const float4*)(W_enc + (size_t)(ks * 32 + dl) * 512 + nn);
    *(ushort4*)(&ldsT[dl * 520 + nn]) = cvt4(f);
  }
  __syncthreads();
  for (int idx = tid; idx < 16384; idx += 256) {
    int kq = idx >> 12;
    int n  = (idx >> 3) & 511;
    int e  = idx & 7;
    Bst[(size_t)ks * 16384 + idx] = ldsT[(kq * 8 + e) * 520 + n];
  }
}

// ---------------- K1: att2[n][a] = b_dec[a] + b_enc[a] + prev_h[n]@W_dec[:,a]
__global__ void att2_k(const float* __restrict__ prev_h,
                       const float* __restrict__ W_dec,
                       const float* __restrict__ b_dec,
                       const float* __restrict__ b_enc,
                       float* __restrict__ att2) {
  const int n = blockIdx.x, tid = threadIdx.x;
  __shared__ float ph[512];
  ph[tid]       = prev_h[n * 512 + tid];
  ph[tid + 256] = prev_h[n * 512 + tid + 256];
  __syncthreads();
  float a0 = b_dec[tid] + b_enc[tid];
  float a1 = b_dec[tid + 256] + b_enc[tid + 256];
  #pragma unroll 8
  for (int h = 0; h < 512; h++) {
    float p = ph[h];
    a0 = fmaf(p, W_dec[h * 512 + tid], a0);
    a1 = fmaf(p, W_dec[h * 512 + tid + 256], a1);
  }
  att2[n * 512 + tid] = a0;
  att2[n * 512 + tid + 256] = a1;
}

__global__ void zero_scores_k(float* __restrict__ s) {
  s[blockIdx.x * 256 + threadIdx.x] = 0.f;
}

// ---------------- K2: pipelined MFMA GEMM + fused relu/W_tot reduce
// grid 1568 = 49 supertiles * (4 nt * 8 m); block 256 = 4 waves (2x2)
__global__ __launch_bounds__(256, 3) void score_gemm_k(
    const float* __restrict__ feature, const u16* __restrict__ Bst,
    const float* __restrict__ att2, const float* __restrict__ W_tot,
    float* __restrict__ scores) {
  __shared__ __align__(16) u16 sA[2][4 * KQP];   // [buf][kq][row=128][8]
  __shared__ __align__(16) u16 sB[2][4 * KQP];   // [buf][kq][col=128][8]
  __shared__ float sRed[2][128];

  const int tid = threadIdx.x;
  const int b = blockIdx.x;
  // XCD swizzle: b = st*32 + nt*8 + mi8 ; XCD = b%8 = mi8 — the 4 nt
  // siblings of m-panel (st,mi8) are 8 apart (same XCD, near-simultaneous).
  const int mt = (b >> 5) * 8 + (b & 7);
  const int nt = (b >> 3) & 3;
  const int r0 = mt << 7, n0 = nt << 7;
  const int wid = tid >> 6, lane = tid & 63;
  const int wgm = wid >> 1, wgn = wid & 1;
  const int quad = lane >> 4, cid = lane & 15;

  // A staging: lane reads row (tid>>3)+{0,32,64,96}, float4 #(tid&7)
  const int arow = tid >> 3, akk4 = tid & 7;
  const float* gA = feature + (size_t)(r0 + arow) * 2048 + akk4 * 4;
  const int wAoff = (akk4 >> 1) * KQP + (arow << 3) + ((akk4 & 1) << 2);

  // B staging via global_load_lds: wave w handles kq-plane w (2048 B)
  const u16* gBlane = Bst + (size_t)wid * 4096 + ((size_t)n0 << 3) + lane * 8;

  // fragment bases
  const int abase = quad * KQP + (((wgm << 6) + cid) << 3);
  const int bbase = quad * KQP + (((wgn << 6) + cid) << 3);

  f32x4 zero = {0.f, 0.f, 0.f, 0.f};
  f32x4 acc[4][4];
  #pragma unroll
  for (int i = 0; i < 4; i++)
    #pragma unroll
    for (int j = 0; j < 4; j++) acc[i][j] = zero;

  float4 a0, a1, a2, a3;
  // prologue: A regs + B glds for ks=0 (into buf 0)
  {
    const float* p = gA;
    a0 = *(const float4*)(p);
    a1 = *(const float4*)(p + 32 * 2048);
    a2 = *(const float4*)(p + 64 * 2048);
    a3 = *(const float4*)(p + 96 * 2048);
    u16* dst = &sB[0][wid * KQP];
    glds16(gBlane, dst);
    glds16(gBlane + 512, dst + 512);
  }

  for (int ks = 0; ks < 64; ks++) {
    const int buf = ks & 1;
    // stage A regs (loaded last iter) into LDS
    u16* wa = &sA[buf][wAoff];
    *(ushort4*)(wa)       = cvt4(a0);
    *(ushort4*)(wa + 256) = cvt4(a1);
    *(ushort4*)(wa + 512) = cvt4(a2);
    *(ushort4*)(wa + 768) = cvt4(a3);
    __syncthreads();   // A writes visible; vmcnt(0) drain lands B glds of ks

    if (ks < 63) {     // prefetch ks+1 while computing ks
      const float* p = gA + (ks + 1) * 32;
      a0 = *(const float4*)(p);
      a1 = *(const float4*)(p + 32 * 2048);
      a2 = *(const float4*)(p + 64 * 2048);
      a3 = *(const float4*)(p + 96 * 2048);
      const u16* src = gBlane + (size_t)(ks + 1) * 16384;
      u16* dst = &sB[buf ^ 1][wid * KQP];
      glds16(src, dst);
      glds16(src + 512, dst + 512);
    }

    const u16* sa = &sA[buf][abase];
    const u16* sb = &sB[buf][bbase];
    short8 af[4], bfr[4];
    #pragma unroll
    for (int mi = 0; mi < 4; mi++)
      af[mi] = *(const short8*)(sa + (mi << 7));
    #pragma unroll
    for (int ni = 0; ni < 4; ni++)
      bfr[ni] = *(const short8*)(sb + (ni << 7));
    #pragma unroll
    for (int mi = 0; mi < 4; mi++)
      #pragma unroll
      for (int ni = 0; ni < 4; ni++)
        acc[mi][ni] = __builtin_amdgcn_mfma_f32_16x16x32_bf16(
            af[mi], bfr[ni], acc[mi][ni], 0, 0, 0);
  }

  // epilogue: s[row] = sum_cols W_tot[col]*relu(acc + att2[n(row)][col])
  float wt[4];
  #pragma unroll
  for (int ni = 0; ni < 4; ni++)
    wt[ni] = W_tot[n0 + (wgn << 6) + ni * 16 + cid];

  #pragma unroll
  for (int mi = 0; mi < 4; mi++) {
    #pragma unroll
    for (int reg = 0; reg < 4; reg++) {
      int row_local = (wgm << 6) + mi * 16 + quad * 4 + reg;
      int row_flat = r0 + row_local;
      int nb = row_flat / 196;
      const float* a2r = att2 + nb * 512 + n0 + (wgn << 6);
      float s = 0.f;
      #pragma unroll
      for (int ni = 0; ni < 4; ni++) {
        float v = acc[mi][ni][reg] + a2r[ni * 16 + cid];
        s += fmaxf(v, 0.f) * wt[ni];
      }
      s += __shfl_xor(s, 1); s += __shfl_xor(s, 2);
      s += __shfl_xor(s, 4); s += __shfl_xor(s, 8);
      if (cid == 0) sRed[wgn][row_local] = s;
    }
  }
  __syncthreads();
  if (tid < 128) atomicAdd(&scores[r0 + tid], sRed[0][tid] + sRed[1][tid]);
}

// ---------------- K3: softmax over L per n
__global__ void softmax_k(const float* __restrict__ scores,
                          float* __restrict__ alpha) {
  const int n = blockIdx.x, tid = threadIdx.x;
  __shared__ float red[8];
  float s = (tid < LQ) ? scores[n * LQ + tid] : -1e30f;
  float m = s;
  for (int o = 32; o; o >>= 1) m = fmaxf(m, __shfl_xor(m, o));
  if ((tid & 63) == 0) red[tid >> 6] = m;
  __syncthreads();
  m = fmaxf(fmaxf(red[0], red[1]), fmaxf(red[2], red[3]));
  float e = (tid < LQ) ? __expf(s - m) : 0.f;
  float t = e;
  for (int o = 32; o; o >>= 1) t += __shfl_xor(t, o);
  if ((tid & 63) == 0) red[4 + (tid >> 6)] = t;
  __syncthreads();
  t = red[4] + red[5] + red[6] + red[7];
  if (tid < LQ) alpha[n * LQ + tid] = e / t;
}

// ---------------- K4: weighted_feature[n][d] = sum_l alpha[l]*feature[n][l][d]
__global__ void wsum_k(const float* __restrict__ feature,
                       const float* __restrict__ alpha,
                       float* __restrict__ out) {
  const int n = blockIdx.x >> 1, half = blockIdx.x & 1;
  const int tid = threadIdx.x;
  __shared__ float al[LQ];
  if (tid < LQ) al[tid] = alpha[n * LQ + tid];
  __syncthreads();
  const float* fp = feature + (size_t)n * LQ * DDIM + half * 1024 + tid * 4;
  float4 acc = {0.f, 0.f, 0.f, 0.f};
  #pragma unroll 4
  for (int l = 0; l < LQ; l++) {
    float a = al[l];
    float4 f = *(const float4*)(fp + (size_t)l * DDIM);
    acc.x = fmaf(a, f.x, acc.x); acc.y = fmaf(a, f.y, acc.y);
    acc.z = fmaf(a, f.z, acc.z); acc.w = fmaf(a, f.w, acc.w);
  }
  *(float4*)(out + n * DDIM + half * 1024 + tid * 4) = acc;
}

extern "C" void kernel_launch(void* const* d_in, const int* in_sizes, int n_in,
                              void* d_out, int out_size, void* d_ws, size_t ws_size,
                              hipStream_t stream) {
  const float* feature = (const float*)d_in[0];
  const float* prev_h  = (const float*)d_in[1];
  const float* W_enc   = (const float*)d_in[2];
  const float* b_enc   = (const float*)d_in[3];
  const float* W_dec   = (const float*)d_in[4];
  const float* b_dec   = (const float*)d_in[5];
  const float* W_tot   = (const float*)d_in[6];
  // d_in[7] = b_tot: softmax-invariant, unused

  float* out   = (float*)d_out;
  float* wf    = out;
  float* alpha = out + WF_N;

  char* ws = (char*)d_ws;
  u16*   Bst    = (u16*)ws;                                 // 2 MB
  float* att2   = (float*)(ws + (2u << 20));                // 512 KB
  float* scores = (float*)(ws + (2u << 20) + (512u << 10)); // 200704 B

  prepB_k<<<64, 256, 0, stream>>>(W_enc, Bst);
  att2_k<<<256, 256, 0, stream>>>(prev_h, W_dec, b_dec, b_enc, att2);
  zero_scores_k<<<196, 256, 0, stream>>>(scores);
  score_gemm_k<<<1568, 256, 0, stream>>>(feature, Bst, att2, W_tot, scores);
  softmax_k<<<256, 256, 0, stream>>>(scores, alpha);
  wsum_k<<<512, 256, 0, stream>>>(feature, alpha, wf);
}